// Round 6
// baseline (543.487 us; speedup 1.0000x reference)
//
#include <hip/hip_runtime.h>
#include <hip/hip_bf16.h>
#include <hip/hip_cooperative_groups.h>

namespace cg = cooperative_groups;

#define B_  32
#define S_  1024
#define H_  512      // == F
#define ML_ 4096

typedef short short8 __attribute__((ext_vector_type(8)));
typedef float floatx4 __attribute__((ext_vector_type(4)));

// ---- output layout (flat float32 view) ----
constexpr size_t OFF_LOGDUR = (size_t)B_ * ML_ * H_;        // 67108864
constexpr size_t OFF_DUR    = OFF_LOGDUR + (size_t)B_ * S_;
constexpr size_t OFF_TLEN   = OFF_DUR + (size_t)B_ * S_;
constexpr size_t OFF_TMASK  = OFF_TLEN + B_;

// ---- scratch staged inside d_out's expanded region (bytes) ----
constexpr size_t XP_BYTES = (size_t)B_ * 1026 * 512 * 2;    // 33,619,968
constexpr size_t WT_BYTES = (size_t)3 * 512 * 512 * 2;      // 1,572,864
constexpr size_t OFF_XP   = 0;
constexpr size_t OFF_H1P  = XP_BYTES;
constexpr size_t OFF_WT1  = 2 * XP_BYTES;
constexpr size_t OFF_WT2  = 2 * XP_BYTES + WT_BYTES;        // ends ~70.4 MB < 268 MB

// ---- d_ws layout (bytes) ----
constexpr size_t WS_CSUM = 0;                                // 131072
constexpr size_t WS_SUMS = 131072;                           // 8 B
constexpr size_t WS_IDX  = 132096;                           // 524288
constexpr size_t WS_NEED_IDX = WS_IDX + (size_t)B_ * ML_ * 4;

// ---- LDS layout of the fused conv kernel (bytes, within 160 KB) ----
constexpr int LA0 = 0;          // A ping   16384
constexpr int LA1 = 16384;      // A pong   16384
constexpr int LB0 = 32768;      // B ping   65536
constexpr int LB1 = 98304;      // B pong   65536
constexpr int LSB = 32768;      // epilogue store staging (66,560 B) aliases B0
constexpr int LR1 = 110592;     // red1 4096  (aliases tail of B1)
constexpr int LR2 = 114688;     // red2 4096
constexpr int LR3 = 118784;     // red3 4096

__device__ __forceinline__ float wave_red(float v) {
#pragma unroll
    for (int o = 32; o > 0; o >>= 1) v += __shfl_down(v, o, 64);
    return v;
}

__device__ __forceinline__ unsigned short f2b(float f) {
    __hip_bfloat16 h = __float2bfloat16(f);
    return *reinterpret_cast<unsigned short*>(&h);
}

__device__ __forceinline__ void gld16(const void* g, void* l) {
    __builtin_amdgcn_global_load_lds(
        (const __attribute__((address_space(1))) unsigned int*)g,
        (__attribute__((address_space(3))) unsigned int*)l, 16, 0, 0);
}

__device__ __forceinline__ void wait0_barrier() {
    asm volatile("s_waitcnt vmcnt(0)\n\ts_barrier" ::: "memory");
}

// ===================== prep kernels =====================

__global__ __launch_bounds__(256) void cast_x_kernel(
    const float* __restrict__ x, unsigned short* __restrict__ Xp,
    unsigned short* __restrict__ H1p) {
    const int tid = threadIdx.x;
    if (blockIdx.x < 8192) {
        size_t gid = (size_t)blockIdx.x * 256 + tid;
        size_t i8  = gid * 8;
        int row = (int)(i8 >> 9);
        int col = (int)(i8 & 511);
        int b = row >> 10, s = row & 1023;
        float4 v0 = *(const float4*)(x + i8);
        float4 v1 = *(const float4*)(x + i8 + 4);
        unsigned short u[8];
        u[0] = f2b(v0.x); u[1] = f2b(v0.y); u[2] = f2b(v0.z); u[3] = f2b(v0.w);
        u[4] = f2b(v1.x); u[5] = f2b(v1.y); u[6] = f2b(v1.z); u[7] = f2b(v1.w);
        *(uint4*)(Xp + ((size_t)b * 1026 + 1 + s) * 512 + col) = *(const uint4*)u;
    } else {
        int slot = (blockIdx.x - 8192) * 256 + tid;
        int row  = slot >> 6, seg = slot & 63;
        unsigned short* p = (row >> 6) ? H1p : Xp;
        int rr = row & 63;
        int b = rr >> 1, r = (rr & 1) ? 1025 : 0;
        uint4 z; z.x = 0; z.y = 0; z.z = 0; z.w = 0;
        *(uint4*)(p + ((size_t)(b * 1026 + r)) * 512 + seg * 8) = z;
    }
}

__global__ __launch_bounds__(256) void transpose_w_kernel(
    const float* __restrict__ W1, const float* __restrict__ W2,
    unsigned short* __restrict__ Wt1, unsigned short* __restrict__ Wt2) {
    __shared__ float t[32][33];
    int z = blockIdx.z;
    const float* W = (z < 3) ? W1 : W2;
    unsigned short* Wt = (z < 3) ? Wt1 : Wt2;
    int k  = (z < 3) ? z : z - 3;
    int h0 = blockIdx.x * 32, f0 = blockIdx.y * 32;
    int tx = threadIdx.x & 31, ty = threadIdx.x >> 5;
    const float* Wk = W + (size_t)k * 512 * 512;
    unsigned short* Wtk = Wt + (size_t)k * 512 * 512;
#pragma unroll
    for (int i = 0; i < 4; ++i)
        t[ty + 8 * i][tx] = Wk[(size_t)(h0 + ty + 8 * i) * 512 + f0 + tx];
    __syncthreads();
#pragma unroll
    for (int i = 0; i < 4; ++i)
        Wtk[(size_t)(f0 + ty + 8 * i) * 512 + h0 + tx] = f2b(t[tx][ty + 8 * i]);
}

__global__ __launch_bounds__(64) void sums_kernel(
    const float* __restrict__ g, const float* __restrict__ be,
    const float* __restrict__ lw, float* __restrict__ out) {
    int t = threadIdx.x;
    float a = 0.f, c = 0.f;
    for (int f = t; f < 512; f += 64) { a += g[f] * lw[f]; c += be[f] * lw[f]; }
    a = wave_red(a); c = wave_red(c);
    if (t == 0) { out[0] = a; out[1] = c; }
}

// ============ fused conv+bias+ReLU+LN phase (bf16 MFMA, pipelined) ===========
// 512 threads (8 waves), tile M=128 x N=512, 1 block/CU (160 KB LDS).
// K-loop: 24 chunks, BOTH A and B double-buffered; prefetch issued right after
// the top barrier -> full compute-phase latency window; only in-loop vmem ops
// are the 10 gld16/wave, so vmcnt(0) at the top drains exactly the cur chunk.
template <bool LOGDUR>
__device__ __forceinline__ void conv_phase(
    unsigned char* SH,
    const unsigned short* __restrict__ Xp,   // [B][1026][512] padded bf16
    const unsigned short* __restrict__ Wt,   // [3][512][512] f-major bf16
    const float* __restrict__ bias,
    const float* __restrict__ gamma,
    const float* __restrict__ beta,
    unsigned short* __restrict__ Op,
    const float* __restrict__ lin_w,
    const float* __restrict__ lin_b,
    const float* __restrict__ sums,
    const int* __restrict__ src_lens,
    float* __restrict__ log_dur) {
    const int tid  = threadIdx.x;
    const int w    = tid >> 6;
    const int lane = tid & 63;
    const int lr   = lane & 15;
    const int lg   = lane >> 4;
    const int b    = blockIdx.x >> 3;
    const int sb   = (blockIdx.x & 7) * 128;
    const int phase = (blockIdx.x >> 3) % 24;

    const unsigned short* Xblk = Xp + ((size_t)b * 1026 + sb) * 512;

    floatx4 acc[8][4];
#pragma unroll
    for (int mt = 0; mt < 8; ++mt)
#pragma unroll
        for (int nt = 0; nt < 4; ++nt) acc[mt][nt] = (floatx4){0.f, 0.f, 0.f, 0.f};

    auto stageB = [&](int kk, int buf) {
        const int k  = kk >> 3;
        const int hc = (kk & 7) * 64;
        const unsigned short* Wk = Wt + (size_t)k * 512 * 512;
        unsigned char* dst = SH + (buf ? LB1 : LB0);
#pragma unroll
        for (int j2 = 0; j2 < 8; ++j2) {
            int fbase = w * 64 + j2 * 8;
            int f  = fbase + (lane >> 3);
            int cg = (lane & 7) ^ (f & 7);
            gld16(Wk + (size_t)f * 512 + hc + cg * 8, dst + fbase * 128);
        }
    };
    auto stageA = [&](int kk, int buf) {
        const int k  = kk >> 3;
        const int hc = (kk & 7) * 64;
        unsigned char* dst = SH + (buf ? LA1 : LA0);
#pragma unroll
        for (int j2 = 0; j2 < 2; ++j2) {
            int rowbase = w * 16 + j2 * 8;
            int row = rowbase + (lane >> 3);
            int cg  = (lane & 7) ^ (row & 7);
            gld16(Xblk + (size_t)(row + k) * 512 + hc + cg * 8, dst + rowbase * 128);
        }
    };

    int kk = phase;
    stageB(kk, 0);
    stageA(kk, 0);

    int bufA = 0, bufB = 0;
    for (int i = 0; i < 24; ++i) {
        wait0_barrier();            // cur landed everywhere; all waves past compute(i-1)
        if (i < 23) {
            int nk = kk + 1; if (nk >= 24) nk -= 24;
            stageB(nk, bufB ^ 1);   // prefetch into the buffers nobody reads this iter
            stageA(nk, bufA ^ 1);
            kk = nk;
            __builtin_amdgcn_sched_barrier(0);   // keep prefetch issue above compute
        }
        const unsigned char* Abuf = SH + (bufA ? LA1 : LA0);
        const unsigned char* Bbuf = SH + (bufB ? LB1 : LB0);
#pragma unroll
        for (int j = 0; j < 2; ++j) {
            const int xt = ((j * 4 + lg) ^ (lr & 7)) * 16;
            short8 af[8], bf[4];
#pragma unroll
            for (int mt = 0; mt < 8; ++mt)
                af[mt] = *(const short8*)(Abuf + (mt * 16 + lr) * 128 + xt);
#pragma unroll
            for (int nt = 0; nt < 4; ++nt)
                bf[nt] = *(const short8*)(Bbuf + (w * 64 + nt * 16 + lr) * 128 + xt);
#pragma unroll
            for (int mt = 0; mt < 8; ++mt)
#pragma unroll
                for (int nt = 0; nt < 4; ++nt)
                    acc[mt][nt] = __builtin_amdgcn_mfma_f32_16x16x32_bf16(
                        af[mt], bf[nt], acc[mt][nt], 0, 0, 0);
        }
        bufA ^= 1; bufB ^= 1;
    }
    __syncthreads();

    float (*red1)[8] = (float(*)[8])(SH + LR1);
    float (*red2)[8] = (float(*)[8])(SH + LR2);
    float (*red3)[8] = (float(*)[8])(SH + LR3);

    // ---- epilogue: bias + ReLU, per-row stats ----
    float bia[4], gam[4], bet[4], glw[4];
#pragma unroll
    for (int nt = 0; nt < 4; ++nt) {
        int f = w * 64 + nt * 16 + lr;
        bia[nt] = bias[f]; gam[nt] = gamma[f]; bet[nt] = beta[f];
        if (LOGDUR) glw[nt] = gam[nt] * lin_w[f];
    }
#pragma unroll
    for (int mt = 0; mt < 8; ++mt)
#pragma unroll
        for (int nt = 0; nt < 4; ++nt)
#pragma unroll
            for (int r = 0; r < 4; ++r)
                acc[mt][nt][r] = fmaxf(acc[mt][nt][r] + bia[nt], 0.f);

#pragma unroll
    for (int mt = 0; mt < 8; ++mt)
#pragma unroll
        for (int r = 0; r < 4; ++r) {
            float p1 = 0.f, p2 = 0.f, p3 = 0.f;
#pragma unroll
            for (int nt = 0; nt < 4; ++nt) {
                float v = acc[mt][nt][r];
                p1 += v; p2 += v * v;
                if (LOGDUR) p3 += v * glw[nt];
            }
#pragma unroll
            for (int m = 1; m < 16; m <<= 1) {
                p1 += __shfl_xor(p1, m, 64);
                p2 += __shfl_xor(p2, m, 64);
                if (LOGDUR) p3 += __shfl_xor(p3, m, 64);
            }
            if (lr == 0) {
                int row = mt * 16 + lg * 4 + r;
                red1[row][w] = p1; red2[row][w] = p2;
                if (LOGDUR) red3[row][w] = p3;
            }
        }
    __syncthreads();

    if constexpr (!LOGDUR) {
        unsigned char* SB = SH + LSB;
        unsigned short* Oblk = Op + ((size_t)b * 1026 + 1 + sb) * 512;
#pragma unroll
        for (int half = 0; half < 2; ++half) {
#pragma unroll
            for (int mi = 0; mi < 4; ++mi) {
                int mt = half * 4 + mi;
#pragma unroll
                for (int r = 0; r < 4; ++r) {
                    int row = mt * 16 + lg * 4 + r;
                    float s1 = 0.f, s2 = 0.f;
#pragma unroll
                    for (int ww = 0; ww < 8; ++ww) { s1 += red1[row][ww]; s2 += red2[row][ww]; }
                    float mu = s1 * (1.f / 512.f);
                    float rstd = rsqrtf(s2 * (1.f / 512.f) - mu * mu + 1e-5f);
#pragma unroll
                    for (int nt = 0; nt < 4; ++nt) {
                        float y = (acc[mt][nt][r] - mu) * rstd * gam[nt] + bet[nt];
                        ((unsigned short*)SB)[(row - half * 64) * 520 + w * 64 + nt * 16 + lr] = f2b(y);
                    }
                }
            }
            __syncthreads();
            for (int it = tid; it < 4096; it += 512) {
                int rr = it >> 6, seg = it & 63;
                uint4 v = *(const uint4*)(SB + rr * 1040 + seg * 16);
                *(uint4*)(Oblk + (size_t)(half * 64 + rr) * 512 + seg * 8) = v;
            }
            __syncthreads();
        }
    } else {
        if (tid < 128) {
            int row = tid;
            float s1 = 0.f, s2 = 0.f, s3 = 0.f;
#pragma unroll
            for (int ww = 0; ww < 8; ++ww) {
                s1 += red1[row][ww]; s2 += red2[row][ww]; s3 += red3[row][ww];
            }
            float mu   = s1 * (1.f / 512.f);
            float rstd = rsqrtf(s2 * (1.f / 512.f) - mu * mu + 1e-5f);
            float val  = rstd * (s3 - mu * sums[0]) + sums[1] + lin_b[0];
            int s = sb + row;
            log_dur[b * S_ + s] = (s >= src_lens[b]) ? 0.f : val;
        }
    }
}

// Both convs in one cooperative dispatch (grid-wide sync between them).
__global__ __launch_bounds__(512, 2) void conv_pair_coop(
    const unsigned short* Xp, const unsigned short* Wt1, const unsigned short* Wt2,
    const float* c1b, const float* g1, const float* b1, unsigned short* H1p,
    const float* c2b, const float* g2, const float* b2,
    const float* lin_w, const float* lin_b, const float* sums,
    const int* src_lens, float* log_dur) {
    __shared__ __align__(16) unsigned char SH[163840];
    conv_phase<false>(SH, Xp, Wt1, c1b, g1, b1, H1p,
                      nullptr, nullptr, nullptr, nullptr, nullptr);
    cg::this_grid().sync();
    conv_phase<true>(SH, H1p, Wt2, c2b, g2, b2, nullptr,
                     lin_w, lin_b, sums, src_lens, log_dur);
}

// ===================== scan (+ idx scatter) =====================

__global__ __launch_bounds__(256) void scan_kernel(
    const int* __restrict__ duration, const int* __restrict__ src_lens,
    int* __restrict__ csum, int* __restrict__ idx, int do_idx,
    float* __restrict__ dur_out, float* __restrict__ tlen_out,
    float* __restrict__ tmask_out) {
    const int b = blockIdx.x, t = threadIdx.x;
    __shared__ int lds[256];
    __shared__ int total_sh;

    const int slen = src_lens[b];
    int loc[4];
    const int sb = t * 4;
#pragma unroll
    for (int i = 0; i < 4; ++i) {
        int s = sb + i;
        loc[i] = (s < slen) ? duration[b * S_ + s] : 0;
    }
    int tsum = loc[0] + loc[1] + loc[2] + loc[3];

    lds[t] = tsum;
    __syncthreads();
    for (int off = 1; off < 256; off <<= 1) {
        int v = (t >= off) ? lds[t - off] : 0;
        __syncthreads();
        lds[t] += v;
        __syncthreads();
    }
    int incl = lds[t];
    if (t == 255) total_sh = incl;

    int run = incl - tsum;
#pragma unroll
    for (int i = 0; i < 4; ++i) {
        int start = run;
        run += loc[i];
        csum[b * S_ + sb + i]    = run;
        dur_out[b * S_ + sb + i] = (float)loc[i];
        if (do_idx)
            for (int q = start; q < run; ++q) idx[b * ML_ + q] = sb + i;
    }
    __syncthreads();
    const int total = total_sh;
    if (t == 0) tlen_out[b] = (float)total;
    for (int p = t; p < ML_; p += 256) tmask_out[b * ML_ + p] = (p >= total) ? 1.f : 0.f;
}

// ===================== expand =====================

__global__ __launch_bounds__(256) void expand_idx_kernel(
    const float* __restrict__ x, const int* __restrict__ csum,
    const int* __restrict__ idx, float* __restrict__ out) {
    const int tid  = threadIdx.x;
    const int row  = blockIdx.x * 2 + (tid >> 7);
    const int lane = tid & 127;
    const int b = row >> 12;
    const int p = row & (ML_ - 1);
    const int total = csum[b * S_ + S_ - 1];
    float4 v = make_float4(0.f, 0.f, 0.f, 0.f);
    if (p < total) {
        int ir = idx[b * ML_ + p];
        v = ((const float4*)x)[(size_t)(b * S_ + ir) * (H_ / 4) + lane];
    }
    ((float4*)out)[(size_t)row * (H_ / 4) + lane] = v;
}

__global__ __launch_bounds__(256) void expand_kernel(
    const float* __restrict__ x, const int* __restrict__ csum,
    float* __restrict__ out) {
    const int tid  = threadIdx.x;
    const int row  = blockIdx.x * 2 + (tid >> 7);
    const int lane = tid & 127;
    const int b = row >> 12;
    const int p = row & (ML_ - 1);
    const int* cs = csum + b * S_;
    const int total = cs[S_ - 1];
    int lo = 0, hi = S_;
    while (lo < hi) {
        int mid = (lo + hi) >> 1;
        if (cs[mid] <= p) lo = mid + 1; else hi = mid;
    }
    int ir = lo < (S_ - 1) ? lo : (S_ - 1);
    float4 v = make_float4(0.f, 0.f, 0.f, 0.f);
    if (p < total) v = ((const float4*)x)[(size_t)(b * S_ + ir) * (H_ / 4) + lane];
    ((float4*)out)[(size_t)row * (H_ / 4) + lane] = v;
}

// ===================== launch =====================

extern "C" void kernel_launch(void* const* d_in, const int* in_sizes, int n_in,
                              void* d_out, int out_size, void* d_ws, size_t ws_size,
                              hipStream_t stream) {
    const float* x        = (const float*)d_in[0];
    const int*   duration = (const int*)d_in[1];
    const int*   src_lens = (const int*)d_in[2];
    const float* conv1_w = (const float*)d_in[4];
    const float* conv1_b = (const float*)d_in[5];
    const float* ln1_g   = (const float*)d_in[6];
    const float* ln1_b   = (const float*)d_in[7];
    const float* conv2_w = (const float*)d_in[8];
    const float* conv2_b = (const float*)d_in[9];
    const float* ln2_g   = (const float*)d_in[10];
    const float* ln2_b   = (const float*)d_in[11];
    const float* lin_w   = (const float*)d_in[12];
    const float* lin_b   = (const float*)d_in[13];

    float* out      = (float*)d_out;
    float* expanded = out;
    float* log_dur  = out + OFF_LOGDUR;
    float* dur_out  = out + OFF_DUR;
    float* tlen_out = out + OFF_TLEN;
    float* tmask    = out + OFF_TMASK;

    int*   csum = (int*)((char*)d_ws + WS_CSUM);
    float* sums = (float*)((char*)d_ws + WS_SUMS);
    int*   idx  = (int*)((char*)d_ws + WS_IDX);
    const int use_idx = (ws_size >= WS_NEED_IDX) ? 1 : 0;

    unsigned short* Xp  = (unsigned short*)((char*)d_out + OFF_XP);
    unsigned short* H1p = (unsigned short*)((char*)d_out + OFF_H1P);
    unsigned short* Wt1 = (unsigned short*)((char*)d_out + OFF_WT1);
    unsigned short* Wt2 = (unsigned short*)((char*)d_out + OFF_WT2);

    cast_x_kernel<<<8224, 256, 0, stream>>>(x, Xp, H1p);
    transpose_w_kernel<<<dim3(16, 16, 6), 256, 0, stream>>>(conv1_w, conv2_w, Wt1, Wt2);
    sums_kernel<<<1, 64, 0, stream>>>(ln2_g, ln2_b, lin_w, sums);

    void* kargs[] = {
        (void*)&Xp, (void*)&Wt1, (void*)&Wt2,
        (void*)&conv1_b, (void*)&ln1_g, (void*)&ln1_b, (void*)&H1p,
        (void*)&conv2_b, (void*)&ln2_g, (void*)&ln2_b,
        (void*)&lin_w, (void*)&lin_b, (void*)&sums,
        (void*)&src_lens, (void*)&log_dur };
    hipLaunchCooperativeKernel((const void*)conv_pair_coop,
                               dim3(256), dim3(512), kargs, 0, stream);

    scan_kernel<<<B_, 256, 0, stream>>>(duration, src_lens, csum, idx, use_idx,
                                        dur_out, tlen_out, tmask);
    if (use_idx)
        expand_idx_kernel<<<B_ * ML_ / 2, 256, 0, stream>>>(x, csum, idx, expanded);
    else
        expand_kernel<<<B_ * ML_ / 2, 256, 0, stream>>>(x, csum, expanded);
}